// Round 3
// baseline (1211.305 us; speedup 1.0000x reference)
//
#include <hip/hip_runtime.h>
#include <math.h>

#define NN 1024
#define BATCH 32
#define P 8              // blocks per batch (1 CU each)
#define NW 4             // waves per block
#define THREADS 256
#define DD 32            // diagonals per interval (max valid for SW=65-DD)
#define SW 33            // row stride between waves = 65 - DD
#define SPAN 164         // (NW-1)*SW + 64 = 163, padded
#define NT 64            // intervals (64*32 = 2048 >= 2047 diagonals)
#define GW 0.05f
#define K2 144.2695040888963f           // (1/gamma)*log2(e): scaled domain
#define INV_K2 0.0069314718055994531f   // gamma*ln2
#define BIGS 1.4426950408889634e11f     // 1e9 * K2

#define EXP2F(x) __builtin_amdgcn_exp2f(x)
#define LOG2F(x) __builtin_amdgcn_logf(x)   // v_log_f32 = log2

// Zero the flag+ack arrays (d_ws is poisoned 0xAA before every launch).
__global__ __launch_bounds__(256) void ws_init(int* __restrict__ f) {
    f[threadIdx.x] = 0;
    f[threadIdx.x + 256] = 0;
}

// Overlapped-band wavefront soft-DTW.
// Block (b, p): rows [128p-31, 128p-31+SPAN). Wave w lane l: row base + 33w + l.
// Within an interval of DD=32 diagonals everything is register/shfl local; lanes
// l < 31 go stale and are refreshed at interval end from the band above
// (LDS for waves 1..3, global interface for wave 0 of blocks p>0).
__global__ __launch_bounds__(THREADS) void sdtw_multi(
        const float* __restrict__ inp, const float* __restrict__ tgt,
        float* __restrict__ partial, int* __restrict__ flags,
        int* __restrict__ acks, float2* __restrict__ gx)
{
    __shared__ float xs[NN];
    __shared__ float wl[NN];
    __shared__ float2 exch[2][SPAN];

    const int bid = blockIdx.x;
    const int b = bid & 31;        // same-batch blocks land on one XCD (round-robin % 8)
    const int p = bid >> 5;
    const int tid = threadIdx.x;
    const int w = tid >> 6;
    const int lane = tid & 63;

    for (int t = tid; t < NN; t += THREADS) {
        xs[t] = inp[b * NN + t];
        wl[t] = K2 / (1.0f + __expf(-GW * ((float)t - 512.0f)));  // w(|i-j|)*K2
    }

    const int i = 128 * p - (DD - 1) + SW * w + lane;   // owned row (may be OOB)
    const bool rowValid = (unsigned)i < (unsigned)NN;
    int ic = i < 0 ? 0 : (i >= NN ? NN - 1 : i);
    const float ti = tgt[b * NN + ic];

    float r1 = BIGS, r2 = BIGS;              // R(i, k-1), R(i, k-2) scaled
    float dgp = (i == 0) ? 0.0f : BIGS;      // R(i-1, k-2) carry; R(-1,-1)=0
    float bndUp = BIGS;                      // lane-0 'up' feed for first diag of interval

    __syncthreads();

    const int fidx = b * P + p;              // inbound interface (p > 0)
    const int fout = fidx + 1;               // outbound interface (p < P-1)

    for (int t = 0; t < NT; ++t) {
        float lane0_up = bndUp;
        #pragma unroll
        for (int d = 0; d < DD; ++d) {
            const int k = t * DD + d;
            float up = __shfl_up(r1, 1);
            if (lane == 0) up = lane0_up;
            lane0_up = BIGS;
            const float dg = dgp;
            const float left = r1;
            const int j = k - i;
            const bool jv = (unsigned)j < (unsigned)NN;
            const float x = xs[j & (NN - 1)];
            int ad = i - j; ad = ad < 0 ? -ad : ad; ad = ad > NN - 1 ? NN - 1 : ad;
            const float wv = wl[ad];
            const float diff = ti - x;
            const float dk = diff * diff * wv;
            const float mn = fminf(fminf(dg, up), left);
            const float md = __builtin_amdgcn_fmed3f(dg, up, left);
            const float mx = fmaxf(fmaxf(dg, up), left);
            const float s = 1.0f + EXP2F(mn - md) + EXP2F(mn - mx);
            float r = dk + mn - LOG2F(s);
            r = (jv && rowValid) ? r : BIGS;
            if (k == 2046 && i == NN - 1) partial[b] = r * INV_K2;  // cell (1023,1023)
            r2 = r1; r1 = r; dgp = up;
        }
        if (t == NT - 1) break;

        const int buf = t & 1;
        const int lrow = SW * w + lane;
        // (a) intra-block publish: every valid lane writes its row's (r1,r2)
        if (lane >= DD - 1) exch[buf][lrow] = make_float2(r1, r2);
        // (b) cross-block publish: rows [128(p+1)-32, 128(p+1)) from valid lanes
        if (p < P - 1 && lane >= DD - 1 &&
            i >= 128 * (p + 1) - DD && i < 128 * (p + 1)) {
            if (t >= 2) {                      // back-pressure: slot t&1 free when ack >= t-1
                while (__hip_atomic_load(&acks[fout], __ATOMIC_ACQUIRE,
                                         __HIP_MEMORY_SCOPE_AGENT) < t - 1)
                    __builtin_amdgcn_s_sleep(2);
            }
            const int slot = i - (128 * (p + 1) - DD);
            gx[(fout * 2 + buf) * DD + slot] = make_float2(r1, r2);
        }
        if (p < P - 1 && w >= 2) __threadfence();   // only waves 2,3 publish globally
        __syncthreads();
        if (tid == 0 && p < P - 1)
            __hip_atomic_store(&flags[fout], t + 1, __ATOMIC_RELEASE,
                               __HIP_MEMORY_SCOPE_AGENT);
        // (c) refresh stale lanes for next interval
        if (w > 0) {
            if (lane < DD - 1) { float2 v = exch[buf][lrow]; r1 = v.x; r2 = v.y; }
            float2 bv = exch[buf][SW * w - 1];         // boundary row (broadcast)
            float nd = __shfl_up(r2, 1);
            if (lane == 0)      { bndUp = bv.x; dgp = bv.y; }
            else if (lane <= DD - 2) dgp = nd;
        } else if (p > 0) {
            while (__hip_atomic_load(&flags[fidx], __ATOMIC_ACQUIRE,
                                     __HIP_MEMORY_SCOPE_AGENT) < t + 1)
                __builtin_amdgcn_s_sleep(2);
            const float2* gin = &gx[(fidx * 2 + buf) * DD];
            if (lane < DD - 1) { float2 v = gin[lane + 1]; r1 = v.x; r2 = v.y; }
            float2 bv = make_float2(BIGS, BIGS);
            if (lane == 0) bv = gin[0];
            float nd = __shfl_up(r2, 1);
            if (lane == 0) {
                bndUp = bv.x; dgp = bv.y;
                __hip_atomic_store(&acks[fidx], t + 1, __ATOMIC_RELEASE,
                                   __HIP_MEMORY_SCOPE_AGENT);
            } else if (lane <= DD - 2) dgp = nd;
        } else {
            bndUp = BIGS;   // p==0, w==0: true boundary, never stale
        }
    }
}

__global__ __launch_bounds__(64) void reduce_mean32(const float* __restrict__ partial,
                                                    float* __restrict__ out) {
    float v = (threadIdx.x < BATCH) ? partial[threadIdx.x] : 0.0f;
    #pragma unroll
    for (int off = 32; off > 0; off >>= 1) v += __shfl_down(v, off);
    if (threadIdx.x == 0) out[0] = v * (1.0f / (float)BATCH);
}

extern "C" void kernel_launch(void* const* d_in, const int* in_sizes, int n_in,
                              void* d_out, int out_size, void* d_ws, size_t ws_size,
                              hipStream_t stream) {
    const float* inp = (const float*)d_in[0];  // [B, N, 1]
    const float* tgt = (const float*)d_in[1];  // [B, N, 1]
    float* out = (float*)d_out;                // [1]

    float* partial = (float*)d_ws;                             // 32 floats
    int* flags = (int*)((char*)d_ws + 128);                    // 256 ints
    int* acks  = (int*)((char*)d_ws + 128 + 1024);             // 256 ints
    float2* gx = (float2*)((char*)d_ws + 128 + 2048);          // 256*2*32 float2

    ws_init<<<1, 256, 0, stream>>>(flags);
    sdtw_multi<<<BATCH * P, THREADS, 0, stream>>>(inp, tgt, partial, flags, acks, gx);
    reduce_mean32<<<1, 64, 0, stream>>>(partial, out);
}

// Round 4
// 270.612 us; speedup vs baseline: 4.4762x; 4.4762x over previous
//
#include <hip/hip_runtime.h>
#include <math.h>

#define NN 1024
#define BATCH 32
#define P 8               // blocks per batch
#define NW 4              // waves per block
#define THREADS 256
#define DD 32             // diagonals per interval (needs SW >= DD-1)
#define SW 32             // row stride between waves
#define SPAN 160          // (NW-1)*SW + 64
#define NT 64             // ceil(2047/DD)
#define RB 4              // ring slots per interface
#define GW 0.05f
#define K2 144.2695040888963f            // (1/gamma)*log2(e): scaled domain
#define INV_K2 0.0069314718055994531f    // gamma*ln2
#define BIGS 1.4426950408889634e11f      // 1e9 * K2

#define EXP2F(x) __builtin_amdgcn_exp2f(x)
#define LOG2F(x) __builtin_amdgcn_logf(x)   // v_log_f32 = log2

union F2U { float2 f; unsigned long long u; };

// lanes 1..63: src[lane-1]; lane 0: feed (DPP wave_shr:1, bound_ctrl=false keeps old)
__device__ __forceinline__ float dpp_shr1(float src, float feed) {
    int r = __builtin_amdgcn_update_dpp(__float_as_int(feed), __float_as_int(src),
                                        0x138, 0xF, 0xF, false);
    return __int_as_float(r);
}

__global__ __launch_bounds__(512) void ws_init(int* __restrict__ f) {
    f[threadIdx.x] = 0;   // flags[256] + acks[256]
}

// Overlapped-band wavefront soft-DTW, 8 CUs per batch.
// Block (b,p): wave w lane l owns row i = 128p-31+32w+l. Each interval = 32
// diagonals entirely in registers (DPP shfl); lanes 0..30 of each wave go stale
// and are refreshed at interval end from the wave below (LDS) or from block p-1
// (global ring, RELAXED agent atomics only -- no L2 invalidate/writeback).
__global__ __launch_bounds__(THREADS) void sdtw_pipe8(
        const float* __restrict__ inp, const float* __restrict__ tgt,
        float* __restrict__ partial, int* __restrict__ flags,
        int* __restrict__ acks, unsigned long long* __restrict__ gx)
{
    __shared__ float xs[NN];
    __shared__ float wl[NN];
    __shared__ float2 exch[2][SPAN];

    const int bid = blockIdx.x;
    const int b = bid & 31;
    const int p = bid >> 5;
    const int tid = threadIdx.x;
    const int w = tid >> 6;
    const int lane = tid & 63;

    for (int t = tid; t < NN; t += THREADS) {
        xs[t] = inp[b * NN + t];
        wl[t] = K2 / (1.0f + __expf(-GW * ((float)t - 512.0f)));  // w(|i-j|)*K2
    }

    const int i = 128 * p - (DD - 1) + SW * w + lane;   // owned row (may be OOB)
    const bool rowValid = (unsigned)i < (unsigned)NN;
    int ic = i < 0 ? 0 : (i > NN - 1 ? NN - 1 : i);
    const float ti = tgt[b * NN + ic];

    float r1 = BIGS, r2 = BIGS;             // R(i,k-1), R(i,k-2), scaled by K2
    float dgp = (i == 0) ? 0.0f : BIGS;     // R(i-1,k-2) carry; R(-1,-1)=0
    float bndUp = BIGS;                     // lane-0 'up' feed at interval start
    int ackC = 0;

    __syncthreads();

    const int fin = b * P + p;              // inbound interface (p>0)
    const int fout = fin + 1;               // outbound interface (p<P-1)
    unsigned long long* gout = gx + (size_t)fout * RB * DD;
    const unsigned long long* ginb = gx + (size_t)fin * RB * DD;

    for (int t = 0; t < NT; ++t) {
        // prefetch outbound ack; latency hides behind this interval's compute
        if (w == NW - 1 && p < P - 1 && t >= RB && ackC <= t - RB) {
            ackC = __hip_atomic_load(&acks[fout], __ATOMIC_RELAXED,
                                     __HIP_MEMORY_SCOPE_AGENT);
        }

        #pragma unroll
        for (int d = 0; d < DD; ++d) {
            const int k = t * DD + d;
            const float feed = (d == 0) ? bndUp : BIGS;
            const float up = dpp_shr1(r1, feed);     // R(i-1,k-1)
            const float dg = dgp;
            const float left = r1;
            const int j = k - i;
            const float x = xs[j & (NN - 1)];
            int ad = i - j; ad = ad < 0 ? -ad : ad;
            const float wv = wl[ad & (NN - 1)];
            const float diff = ti - x;
            const float dk = diff * diff * wv;       // K2-scaled cost
            const float mn = fminf(fminf(dg, up), left);
            const float md = __builtin_amdgcn_fmed3f(dg, up, left);
            const float mx = fmaxf(fmaxf(dg, up), left);
            const float s = 1.0f + EXP2F(mn - md) + EXP2F(mn - mx);
            float r = dk + mn - LOG2F(s);
            r = (((unsigned)j < (unsigned)NN) && rowValid) ? r : BIGS;
            r2 = r1; r1 = r; dgp = up;
        }
        if (t == NT - 1) break;

        const int buf = t & 1;
        // intra-block publish: fresh lanes only (lane >= DD-1)
        if (lane >= DD - 1) exch[buf][SW * w + lane] = make_float2(r1, r2);
        // cross-block publish: wave NW-1 lanes 31..62 = rows [128(p+1)-32, 128(p+1))
        if (w == NW - 1 && p < P - 1) {
            if (t >= RB) {
                while (ackC < t - (RB - 1)) {          // slot t&3 free?
                    __builtin_amdgcn_s_sleep(1);
                    ackC = __hip_atomic_load(&acks[fout], __ATOMIC_RELAXED,
                                             __HIP_MEMORY_SCOPE_AGENT);
                }
            }
            if (lane >= DD - 1 && lane < 63) {
                F2U v; v.f = make_float2(r1, r2);
                __hip_atomic_store(&gout[(size_t)(t & (RB - 1)) * DD + (lane - (DD - 1))],
                                   v.u, __ATOMIC_RELAXED, __HIP_MEMORY_SCOPE_AGENT);
            }
            asm volatile("s_waitcnt vmcnt(0)" ::: "memory");   // data drained to L2/coherence pt
            if (lane == 63)
                __hip_atomic_store(&flags[fout], t + 1, __ATOMIC_RELAXED,
                                   __HIP_MEMORY_SCOPE_AGENT);
        }
        __syncthreads();
        // refresh stale lanes (0..30) + boundary feed for next interval
        if (w > 0) {
            if (lane < DD - 1) { float2 v = exch[buf][SW * w + lane]; r1 = v.x; r2 = v.y; }
            float2 bv = exch[buf][SW * w - 1];
            float nd = dpp_shr1(r2, 0.0f);
            if (lane == 0)           { bndUp = bv.x; dgp = bv.y; }
            else if (lane <= DD - 2) dgp = nd;
        } else if (p > 0) {
            int fl;
            do {
                fl = __hip_atomic_load(&flags[fin], __ATOMIC_RELAXED,
                                       __HIP_MEMORY_SCOPE_AGENT);
                if (fl < t + 1) __builtin_amdgcn_s_sleep(1);
            } while (fl < t + 1);
            asm volatile("" ::: "memory");             // don't hoist data loads above poll
            const unsigned long long* gslot = ginb + (size_t)(t & (RB - 1)) * DD;
            if (lane < DD - 1) {
                F2U v; v.u = __hip_atomic_load((unsigned long long*)&gslot[lane + 1],
                                               __ATOMIC_RELAXED, __HIP_MEMORY_SCOPE_AGENT);
                r1 = v.f.x; r2 = v.f.y;
            }
            F2U bv; bv.f = make_float2(BIGS, BIGS);
            if (lane == 0)
                bv.u = __hip_atomic_load((unsigned long long*)&gslot[0],
                                         __ATOMIC_RELAXED, __HIP_MEMORY_SCOPE_AGENT);
            float nd = dpp_shr1(r2, 0.0f);
            if (lane == 0)           { bndUp = bv.f.x; dgp = bv.f.y; }
            else if (lane <= DD - 2) dgp = nd;
            asm volatile("s_waitcnt vmcnt(0)" ::: "memory");   // loads done before ack
            if (lane == 0)
                __hip_atomic_store(&acks[fin], t + 1, __ATOMIC_RELAXED,
                                   __HIP_MEMORY_SCOPE_AGENT);
        } else {
            bndUp = BIGS;   // p==0, w==0: true boundary
        }
    }

    // after t=NT-1: r2 = R(i, 2046); cell (1023,1023) sits at i=1023 (p=7,w=3,lane=62)
    if (i == NN - 1) partial[b] = r2 * INV_K2;
}

__global__ __launch_bounds__(64) void reduce_mean32(const float* __restrict__ partial,
                                                    float* __restrict__ out) {
    float v = (threadIdx.x < BATCH) ? partial[threadIdx.x] : 0.0f;
    #pragma unroll
    for (int off = 32; off > 0; off >>= 1) v += __shfl_down(v, off);
    if (threadIdx.x == 0) out[0] = v * (1.0f / (float)BATCH);
}

extern "C" void kernel_launch(void* const* d_in, const int* in_sizes, int n_in,
                              void* d_out, int out_size, void* d_ws, size_t ws_size,
                              hipStream_t stream) {
    const float* inp = (const float*)d_in[0];  // [B, N, 1]
    const float* tgt = (const float*)d_in[1];  // [B, N, 1]
    float* out = (float*)d_out;                // [1]

    float* partial = (float*)d_ws;                               // 32 floats
    int* flags = (int*)((char*)d_ws + 128);                      // 256 ints
    int* acks  = (int*)((char*)d_ws + 128 + 1024);               // 256 ints
    unsigned long long* gx = (unsigned long long*)((char*)d_ws + 128 + 2048);  // 256*RB*DD u64

    ws_init<<<1, 512, 0, stream>>>(flags);
    sdtw_pipe8<<<BATCH * P, THREADS, 0, stream>>>(inp, tgt, partial, flags, acks, gx);
    reduce_mean32<<<1, 64, 0, stream>>>(partial, out);
}

// Round 5
// 223.386 us; speedup vs baseline: 5.4225x; 1.2114x over previous
//
#include <hip/hip_runtime.h>
#include <math.h>

#define NN 1024
#define BATCH 32
#define P 8               // blocks per batch
#define NW 4              // waves per block
#define THREADS 256
#define DD 32             // diagonals per interval (needs SW >= DD-1, SW+DD <= 65)
#define SW 32             // row stride between waves
#define SPAN 160          // (NW-1)*SW + 64
#define NT 64             // ceil(2047/DD)
#define RB 4              // ring slots per interface
#define GW 0.05f
#define K2 144.2695040888963f            // (1/gamma)*log2(e): scaled domain
#define INV_K2 0.0069314718055994531f    // gamma*ln2
#define BIGS 1.4426950408889634e11f      // 1e9 * K2

#define EXP2F(x) __builtin_amdgcn_exp2f(x)
#define LOG2F(x) __builtin_amdgcn_logf(x)   // v_log_f32 = log2

union F2U { float2 f; unsigned long long u; };

// lanes 1..63 <- src[lane-1]; lane 0 <- oldv[0] (DPP wave_shr:1, bound_ctrl=false)
__device__ __forceinline__ float dppshr(float oldv, float src) {
    return __int_as_float(__builtin_amdgcn_update_dpp(
        __float_as_int(oldv), __float_as_int(src), 0x138, 0xF, 0xF, false));
}

__global__ __launch_bounds__(512) void ws_init(int* __restrict__ f) {
    f[threadIdx.x] = 0;   // flags[256] + acks[256]
}

// Overlapped-band wavefront soft-DTW, 8 CUs per batch (round-4 skeleton).
// New: x via DPP diagonal rotation (re-init per interval; contamination aligns
// with the trapezoid's stale lanes), parity-split weight LUT (stride-1,
// immediate-offset ds_read), entry-only masking via per-d literal compare.
__global__ __launch_bounds__(THREADS) void sdtw_pipe8(
        const float* __restrict__ inp, const float* __restrict__ tgt,
        float* __restrict__ partial, int* __restrict__ flags,
        int* __restrict__ acks, unsigned long long* __restrict__ gx)
{
    __shared__ float xs[NN];
    __shared__ float wlblk[3136];    // [guard 544 | O:1024 | E:1024 | guard 544]
    __shared__ float2 exch[2][SPAN];

    const int bid = blockIdx.x;
    const int b = bid & 31;          // same-batch stages share an XCD (bid%8 = b%8)
    const int p = bid >> 5;
    const int tid = threadIdx.x;
    const int w = tid >> 6;
    const int lane = tid & 63;

    // wl2[m] = K2*sigma(G*(|m-1023|-512)), m = j-i+1023 in [0,2046].
    // O[y]=wl2[2y+1] at blk[544+y]; E[y]=wl2[2y] at blk[544+1024+y].
    for (int tdx = tid; tdx < NN; tdx += THREADS) {
        xs[tdx] = inp[b * NN + tdx];
        float mO = (float)(2 * tdx + 1) - 1023.0f;
        float mE = (float)(2 * tdx) - 1023.0f;
        wlblk[544 + tdx]        = K2 / (1.0f + __expf(-GW * (fabsf(mO) - 512.0f)));
        wlblk[544 + 1024 + tdx] = K2 / (1.0f + __expf(-GW * (fabsf(mE) - 512.0f)));
    }

    const int i = 128 * p - (DD - 1) + SW * w + lane;   // owned row (may be OOB)
    const int i0 = i - lane;                            // wave's base row
    const bool rowValid = (unsigned)i < (unsigned)NN;
    int ic = min(max(i, 0), NN - 1);
    const float ti = tgt[b * NN + ic];
    const int imask = rowValid ? i : 0x3FFFFFFF;        // forces jj0 very negative
    // wp base: word index 544 + q0, q0 = 16t + 511 - i  (t added per interval)
    const float* wpBase = &wlblk[544 + 511 - i];        // i in [-31,1024] -> idx in [31,1086]

    float r1 = BIGS, r2 = BIGS;             // R(i,k-1), R(i,k-2), scaled by K2
    float dgp = (i == 0) ? 0.0f : BIGS;     // R(i-1,k-2) carry; R(-1,-1)=0
    float bndUp = BIGS;                     // lane-0 'up' feed at interval start
    float xv = 0.0f;                        // x[k - i] rotation register
    int ackC = 0;

    __syncthreads();

    const int fin = b * P + p;              // inbound interface (p>0)
    const int fout = fin + 1;               // outbound interface (p<P-1)
    unsigned long long* gout = gx + (size_t)fout * RB * DD;
    const unsigned long long* ginb = gx + (size_t)fin * RB * DD;

    for (int t = 0; t < NT; ++t) {
        // prefetch outbound ack; hides behind this interval's compute
        if (w == NW - 1 && p < P - 1 && t >= RB && ackC <= t - RB) {
            ackC = __hip_atomic_load(&acks[fout], __ATOMIC_RELAXED,
                                     __HIP_MEMORY_SCOPE_AGENT);
        }

        const int kbase = t << 5;
        const float* wp = wpBase + (t << 4);            // q0 += 16 per interval
        // re-init x rotation: lane holds x[kbase-1-i] (clamped; garbage-ok when OOB)
        int c = kbase - 1 - i;  c = min(max(c, 0), NN - 1);
        xv = xs[c];
        // uniform d=0 feed for lane 0: x[kbase - i0]
        int c0 = kbase - i0;    c0 = min(max(c0, 0), NN - 1);
        const float xf0 = xs[c0];
        const int jj0 = kbase - imask;                  // j at d=0 (or very negative)

        #pragma unroll
        for (int d = 0; d < DD; ++d) {
            xv = dppshr((d == 0) ? xf0 : xv, xv);       // x[k-i] flows diagonally
            const float up = dppshr((d == 0) ? bndUp : r1, r1);   // R(i-1,k-1)
            const float dg = dgp;
            const float left = r1;
            const float wv = (d & 1) ? wp[1024 + ((d + 1) >> 1)]  // E[q0+(d+1)/2]
                                     : wp[(d >> 1)];              // O[q0+d/2]
            const float diff = ti - xv;
            const float dk = diff * diff * wv;          // K2-scaled cost
            const float mn = fminf(fminf(dg, up), left);
            const float md = __builtin_amdgcn_fmed3f(dg, up, left);
            const float mx = fmaxf(fmaxf(dg, up), left);
            const float s = 1.0f + EXP2F(mn - md) + EXP2F(mn - mx);
            float r = dk + mn - LOG2F(s);
            r = (jj0 >= -d) ? r : BIGS;                 // entry-side mask only
            r2 = r1; r1 = r; dgp = up;
        }
        if (t == NT - 1) break;

        const int buf = t & 1;
        // intra-block publish: fresh lanes only (lane >= DD-1)
        if (lane >= DD - 1) exch[buf][SW * w + lane] = make_float2(r1, r2);
        // cross-block publish: wave NW-1 lanes 31..62 = rows [128(p+1)-32, 128(p+1))
        if (w == NW - 1 && p < P - 1) {
            if (t >= RB) {
                while (ackC < t - (RB - 1)) {           // slot t&3 free?
                    __builtin_amdgcn_s_sleep(1);
                    ackC = __hip_atomic_load(&acks[fout], __ATOMIC_RELAXED,
                                             __HIP_MEMORY_SCOPE_AGENT);
                }
            }
            if (lane >= DD - 1 && lane < 63) {
                F2U v; v.f = make_float2(r1, r2);
                __hip_atomic_store(&gout[(size_t)(t & (RB - 1)) * DD + (lane - (DD - 1))],
                                   v.u, __ATOMIC_RELAXED, __HIP_MEMORY_SCOPE_AGENT);
            }
            asm volatile("s_waitcnt vmcnt(0)" ::: "memory");   // data drained before flag
            if (lane == 63)
                __hip_atomic_store(&flags[fout], t + 1, __ATOMIC_RELAXED,
                                   __HIP_MEMORY_SCOPE_AGENT);
        }
        __syncthreads();
        // refresh stale lanes (0..30) + boundary feed for next interval
        if (w > 0) {
            if (lane < DD - 1) { float2 v = exch[buf][SW * w + lane]; r1 = v.x; r2 = v.y; }
            float2 bv = exch[buf][SW * w - 1];
            float nd = dppshr(0.0f, r2);
            if (lane == 0)           { bndUp = bv.x; dgp = bv.y; }
            else if (lane <= DD - 2) dgp = nd;
        } else if (p > 0) {
            int fl;
            do {
                fl = __hip_atomic_load(&flags[fin], __ATOMIC_RELAXED,
                                       __HIP_MEMORY_SCOPE_AGENT);
                if (fl < t + 1) __builtin_amdgcn_s_sleep(1);
            } while (fl < t + 1);
            asm volatile("" ::: "memory");             // don't hoist data loads above poll
            const unsigned long long* gslot = ginb + (size_t)(t & (RB - 1)) * DD;
            if (lane < DD - 1) {
                F2U v; v.u = __hip_atomic_load((unsigned long long*)&gslot[lane + 1],
                                               __ATOMIC_RELAXED, __HIP_MEMORY_SCOPE_AGENT);
                r1 = v.f.x; r2 = v.f.y;
            }
            F2U bv; bv.f = make_float2(BIGS, BIGS);
            if (lane == 0)
                bv.u = __hip_atomic_load((unsigned long long*)&gslot[0],
                                         __ATOMIC_RELAXED, __HIP_MEMORY_SCOPE_AGENT);
            float nd = dppshr(0.0f, r2);
            if (lane == 0)           { bndUp = bv.f.x; dgp = bv.f.y; }
            else if (lane <= DD - 2) dgp = nd;
            asm volatile("s_waitcnt vmcnt(0)" ::: "memory");   // loads done before ack
            if (lane == 0)
                __hip_atomic_store(&acks[fin], t + 1, __ATOMIC_RELAXED,
                                   __HIP_MEMORY_SCOPE_AGENT);
        } else {
            bndUp = BIGS;   // p==0, w==0: true boundary
        }
    }

    // after t=NT-1: r2 = R(i, 2046); cell (1023,1023) is at i=1023 (p=7,w=3,lane=62)
    if (i == NN - 1) partial[b] = r2 * INV_K2;
}

__global__ __launch_bounds__(64) void reduce_mean32(const float* __restrict__ partial,
                                                    float* __restrict__ out) {
    float v = (threadIdx.x < BATCH) ? partial[threadIdx.x] : 0.0f;
    #pragma unroll
    for (int off = 32; off > 0; off >>= 1) v += __shfl_down(v, off);
    if (threadIdx.x == 0) out[0] = v * (1.0f / (float)BATCH);
}

extern "C" void kernel_launch(void* const* d_in, const int* in_sizes, int n_in,
                              void* d_out, int out_size, void* d_ws, size_t ws_size,
                              hipStream_t stream) {
    const float* inp = (const float*)d_in[0];  // [B, N, 1]
    const float* tgt = (const float*)d_in[1];  // [B, N, 1]
    float* out = (float*)d_out;                // [1]

    float* partial = (float*)d_ws;                               // 32 floats
    int* flags = (int*)((char*)d_ws + 128);                      // 256 ints
    int* acks  = (int*)((char*)d_ws + 128 + 1024);               // 256 ints
    unsigned long long* gx = (unsigned long long*)((char*)d_ws + 128 + 2048);  // 256*RB*DD u64

    ws_init<<<1, 512, 0, stream>>>(flags);
    sdtw_pipe8<<<BATCH * P, THREADS, 0, stream>>>(inp, tgt, partial, flags, acks, gx);
    reduce_mean32<<<1, 64, 0, stream>>>(partial, out);
}